// Round 3
// baseline (674.594 us; speedup 1.0000x reference)
//
#include <hip/hip_runtime.h>
#include <cstdint>
#include <cstddef>

// ---------------------------------------------------------------------------
// NaiveSDPA: out[n,s,v] = softmax(Q·K^T / 8 + mask) · V ; f32 I/O, bf16 MFMA.
// v9: register-diet + true 4 blocks/CU.
// Diagnosis from r0-r2: occupancy cap is COMBINED arch+acc VGPR (gfx950
// unified file, waves/SIMD halves at 64/128/256 combined). v6/v8 = 92 arch
// + ~64 acc ~= 156 -> 2 waves/SIMD (22% occ) regardless of grid. v7's
// launch_bounds(256,4) forced <=128 but the ~160-reg working set spilled
// 1.4GB scratch. v9 shrinks the working set structurally, then re-applies
// (256,4):
//   - no persistent K/V prefetch regs: next-tile loads issued between
//     softmax and PV (MFMA-covered), packed+written to LDS after PV.
//   - mask loaded per-h (8 regs live) instead of 32-reg upfront block.
//   - kf/exp/pack folded per-h (transients don't coexist).
//   Peak ~118 combined -> 4 waves/SIMD without spills.
// Kept from v7/v8: KV-split x2 (grid 1024 -> 4 blocks/CU now that regs
// allow), ones-MFMA row-sum, setprio around MFMA clusters, combine pass.
// Tripwire: if WRITE_SIZE >> 33MB next profile, the diet failed (spills).
// ---------------------------------------------------------------------------

typedef __attribute__((ext_vector_type(8))) short short8;
typedef __attribute__((ext_vector_type(4))) short short4v;
typedef __attribute__((ext_vector_type(4))) float f32x4;
typedef __attribute__((ext_vector_type(4))) unsigned int uint4v;
typedef __attribute__((ext_vector_type(2))) unsigned int uint2v;

#define DEV __device__ __forceinline__

constexpr int N_B   = 16;
constexpr int S_Q   = 4096;
constexpr int S_KV  = 4096;
constexpr int DH    = 64;
constexpr int BQ    = 128;         // q rows per block (4 waves x 32)
constexpr int BK    = 64;
constexpr int ITERS = S_KV / BK;   // 64
constexpr int KSTR  = 72;          // shorts/row: 144B (skew 4 dwords)
constexpr int VSTR  = 68;          // shorts/row: 136B (16 slots + 4 pad)

#define LOG2E 1.44269504088896340736f

DEV unsigned short f2bf(float f) {           // RNE f32 -> bf16
  union { float f; unsigned int i; } x; x.f = f;
  unsigned int r = x.i + 0x7FFFu + ((x.i >> 16) & 1u);
  return (unsigned short)(r >> 16);
}

#if __has_builtin(__builtin_amdgcn_cvt_pk_bf16_f32)
typedef __attribute__((ext_vector_type(2))) __bf16 bf16x2v;
DEV unsigned int packrne(float a, float b) {   // bf16(a) lo | bf16(b) hi, RNE
  union { bf16x2v v; unsigned int u; } x;
  x.v = __builtin_amdgcn_cvt_pk_bf16_f32(a, b);
  return x.u;
}
#else
DEV unsigned int packrne(float a, float b) {
  union { float f; unsigned int u; } ua, ub; ua.f = a; ub.f = b;
  unsigned int ra = ua.u + 0x7FFFu + ((ua.u >> 16) & 1u);
  unsigned int rb = ub.u + 0x7FFFu + ((ub.u >> 16) & 1u);
  return __builtin_amdgcn_perm(rb, ra, 0x07060302u);
}
#endif

DEV f32x4 mfma16(short4v a, short4v b, f32x4 c) {
#if __has_builtin(__builtin_amdgcn_mfma_f32_16x16x16bf16_1k)
  return __builtin_amdgcn_mfma_f32_16x16x16bf16_1k(a, b, c, 0, 0, 0);
#elif __has_builtin(__builtin_amdgcn_mfma_f32_16x16x16_bf16)
  return __builtin_amdgcn_mfma_f32_16x16x16_bf16(a, b, c, 0, 0, 0);
#else
  asm volatile("v_mfma_f32_16x16x16_bf16 %0, %1, %2, %0\n\ts_nop 7\n\ts_nop 7"
               : "+v"(c) : "v"(a), "v"(b));
  return c;
#endif
}

// stage K tile: thread t owns 16B chunks (r=t>>3, c=t&7) and (r+32, c).
DEV void stageK(unsigned short* buf, const f32x4* kA, int t) {
  const int r0 = t >> 3, c = t & 7;
  uint4v d0, d1;
  d0[0] = packrne(kA[0][0], kA[0][1]); d0[1] = packrne(kA[0][2], kA[0][3]);
  d0[2] = packrne(kA[1][0], kA[1][1]); d0[3] = packrne(kA[1][2], kA[1][3]);
  d1[0] = packrne(kA[2][0], kA[2][1]); d1[1] = packrne(kA[2][2], kA[2][3]);
  d1[2] = packrne(kA[3][0], kA[3][1]); d1[3] = packrne(kA[3][2], kA[3][3]);
  *(uint4v*)&buf[r0 * KSTR + c * 8]        = d0;
  *(uint4v*)&buf[(r0 + 32) * KSTR + c * 8] = d1;
}

// stage V^T: thread t loaded L[i] = V[kv=4*(t>>4)+i][4*(t&15)..+3] (coalesced:
// per phase 16 lanes cover one 256B row segment). Write chunk a=t>>4 of
// vcol=4x+j (x=t&15) at slot (a+x)&15: banks = 10x+const mod 32 -> 16
// distinct per phase, conflict-free.
DEV void stageV(unsigned short* buf, const f32x4* L, int t) {
  const int a = t >> 4;           // kv-chunk
  const int x = t & 15;           // vcol>>2
  const int slot = (a + x) & 15;
#pragma unroll
  for (int j = 0; j < 4; ++j) {
    uint2v d;
    d[0] = packrne(L[0][j], L[1][j]);
    d[1] = packrne(L[2][j], L[3][j]);
    *(uint2v*)&buf[(x * 4 + j) * VSTR + slot * 4] = d;
  }
}

__global__ __launch_bounds__(256, 4)
void sdpa_fwd(const float* __restrict__ Qg,
              const float* __restrict__ Kg,
              const float* __restrict__ Vg,
              const float* __restrict__ Mg,
              float* __restrict__ Ob,    // Og (finalize) or ws acc base
              float* __restrict__ Lb,    // nullptr (finalize) or ws l base
              int nIter)
{
  __shared__ __align__(16) unsigned short ldsK[2][BK * KSTR];  // 2 x 9216 B
  __shared__ __align__(16) unsigned short ldsV[2][DH * VSTR];  // 2 x 8704 B

  const int n    = blockIdx.y;
  const int q0   = blockIdx.x * BQ;
  const int z    = blockIdx.z;                   // kv half
  const size_t kvbase = (size_t)z * (size_t)nIter * BK;
  const int t    = threadIdx.x;
  const int w    = t >> 6;         // wave: owns q rows q0+32w .. +31
  const int lane = t & 63;
  const int l15  = lane & 15;
  const int quad = lane >> 4;

  // ---- Q B-frags for two 16-q streams: qA (q=q0+32w+l15), qB (+16)
  short8 qfA0, qfA1, qfB0, qfB1;
  {
    const float* qp =
        Qg + ((size_t)n * S_Q + (size_t)(q0 + w * 32 + l15)) * DH + quad * 8;
#pragma unroll
    for (int j = 0; j < 8; ++j) {
      qfA0[j] = (short)f2bf(qp[j]);
      qfA1[j] = (short)f2bf(qp[32 + j]);
      qfB0[j] = (short)f2bf(qp[16 * DH + j]);
      qfB1[j] = (short)f2bf(qp[16 * DH + 32 + j]);
    }
  }

  // ---- staging source pointers (both coalesced per 16-lane phase)
  const float* kgp =
      Kg + ((size_t)n * S_KV + kvbase + (size_t)(t >> 3)) * DH + (t & 7) * 8;
  const float* vgp =
      Vg + ((size_t)n * S_KV + kvbase + (size_t)(t >> 4) * 4) * DH + (t & 15) * 4;
  const float* mrowA =
      Mg + (size_t)(q0 + w * 32 + l15) * S_KV + kvbase + quad * 4;
  const float* mrowB = mrowA + (size_t)16 * S_KV;

  // ---- O^T accumulators per stream (C-layout: row v=16nt+quad*4+r, col q)
  f32x4 accA[4], accB[4];
#pragma unroll
  for (int nt = 0; nt < 4; ++nt)
#pragma unroll
    for (int r = 0; r < 4; ++r) { accA[nt][r] = 0.0f; accB[nt][r] = 0.0f; }

  // ---- l accumulators via ones-MFMA: lsum[r] = sum_kv P[kv][q=l15] (all r eq)
  f32x4 lsA = {0.f, 0.f, 0.f, 0.f}, lsB = {0.f, 0.f, 0.f, 0.f};
  const short4v onesf = {(short)0x3F80, (short)0x3F80,
                         (short)0x3F80, (short)0x3F80};  // bf16 1.0

  // ---- prologue: load + stage tile 0 (locals; no persistent prefetch regs)
  {
    f32x4 kA[4], vL[4];
    kA[0] = *(const f32x4*)(kgp);
    kA[1] = *(const f32x4*)(kgp + 4);
    kA[2] = *(const f32x4*)(kgp + 32 * DH);
    kA[3] = *(const f32x4*)(kgp + 32 * DH + 4);
#pragma unroll
    for (int i = 0; i < 4; ++i) vL[i] = *(const f32x4*)(vgp + i * DH);
    stageK(&ldsK[0][0], kA, t);
    stageV(&ldsV[0][0], vL, t);
  }
  __syncthreads();

  for (int it = 0; it < nIter; ++it) {
    const int p   = it & 1;
    const int kv0 = it * BK;
    const bool more = (it + 1 < nIter);

    // ---- phase 1: per-h { kf read, mask load, QK MFMA, exp, pack }
    // transients (kf 16, mask 8, c 8, e 8) live only within one h step.
    short4v pfA[4], pfB[4];
#pragma unroll
    for (int h = 0; h < 4; ++h) {
      const short8 kf0 =
          *(const short8*)&ldsK[p][(l15 + 16 * h) * KSTR + quad * 8];
      const short8 kf1 =
          *(const short8*)&ldsK[p][(l15 + 16 * h) * KSTR + (quad + 4) * 8];
      const f32x4 mA = *(const f32x4*)(mrowA + kv0 + 16 * h);
      const f32x4 mB = *(const f32x4*)(mrowB + kv0 + 16 * h);
      f32x4 cA = {0.f, 0.f, 0.f, 0.f}, cB = {0.f, 0.f, 0.f, 0.f};
      __builtin_amdgcn_s_setprio(1);
      cA = __builtin_amdgcn_mfma_f32_16x16x32_bf16(kf0, qfA0, cA, 0, 0, 0);
      cB = __builtin_amdgcn_mfma_f32_16x16x32_bf16(kf0, qfB0, cB, 0, 0, 0);
      cA = __builtin_amdgcn_mfma_f32_16x16x32_bf16(kf1, qfA1, cA, 0, 0, 0);
      cB = __builtin_amdgcn_mfma_f32_16x16x32_bf16(kf1, qfB1, cB, 0, 0, 0);
      __builtin_amdgcn_s_setprio(0);
      float eA[4], eB[4];
#pragma unroll
      for (int r = 0; r < 4; ++r) {
        eA[r] = __builtin_amdgcn_exp2f(fmaf(cA[r], 0.125f, mA[r]) * LOG2E);
        eB[r] = __builtin_amdgcn_exp2f(fmaf(cB[r], 0.125f, mB[r]) * LOG2E);
      }
      union { uint2v u; short4v s; } ua, ub;
      ua.u[0] = packrne(eA[0], eA[1]); ua.u[1] = packrne(eA[2], eA[3]);
      ub.u[0] = packrne(eB[0], eB[1]); ub.u[1] = packrne(eB[2], eB[3]);
      pfA[h] = ua.s; pfB[h] = ub.s;
    }

    // ---- issue next-tile global loads here: covered by ls+PV MFMAs below,
    // live range spans only the PV phase (~32 regs, peak stays <=128).
    f32x4 kA[4], vL[4];
    if (more) {
      const float* kn = kgp + (size_t)(kv0 + BK) * DH;
      kA[0] = *(const f32x4*)(kn);
      kA[1] = *(const f32x4*)(kn + 4);
      kA[2] = *(const f32x4*)(kn + 32 * DH);
      kA[3] = *(const f32x4*)(kn + 32 * DH + 4);
      const float* vn = vgp + (size_t)(kv0 + BK) * DH;
#pragma unroll
      for (int i = 0; i < 4; ++i) vL[i] = *(const f32x4*)(vn + i * DH);
    }

    __builtin_amdgcn_s_setprio(1);
    // row sums on the matrix pipe (no serial adds / shfl on critical path)
#pragma unroll
    for (int h = 0; h < 4; ++h) {
      lsA = mfma16(onesf, pfA[h], lsA);
      lsB = mfma16(onesf, pfB[h], lsB);
    }

    // PV: O^T += V^T·P^T ; each vf read feeds both streams.
    // vf = V^T[vcol=l15+16nt][kv chunk c=4h+quad] at slot (c + vcol/4)&15
#pragma unroll
    for (int nt = 0; nt < 4; ++nt) {
      const int vcol = l15 + 16 * nt;
      const int xr   = (l15 >> 2) + 4 * nt;
#pragma unroll
      for (int h = 0; h < 4; ++h) {
        const int slot = ((4 * h + quad) + xr) & 15;
        short4v vf = *(const short4v*)&ldsV[p][vcol * VSTR + slot * 4];
        accA[nt] = mfma16(vf, pfA[h], accA[nt]);
        accB[nt] = mfma16(vf, pfB[h], accB[nt]);
      }
    }
    __builtin_amdgcn_s_setprio(0);

    // ---- write-late: pack + ds_write the prefetched tile
    if (more) {
      stageK(&ldsK[p ^ 1][0], kA, t);
      stageV(&ldsV[p ^ 1][0], vL, t);
    }
    __syncthreads();
  }

  // ---- epilogue
  const int qA = q0 + w * 32 + l15;
  if (Lb) {
    // partial: unnormalized acc + l to workspace (combine pass normalizes)
    const size_t NSV = (size_t)N_B * S_Q * DH;
    float* obA = Ob + (size_t)z * NSV + ((size_t)n * S_Q + (size_t)qA) * DH
               + quad * 4;
    float* obB = obA + (size_t)16 * DH;
#pragma unroll
    for (int nt = 0; nt < 4; ++nt) {
      *(f32x4*)(obA + 16 * nt) = accA[nt];
      *(f32x4*)(obB + 16 * nt) = accB[nt];
    }
    if (quad == 0) {
      float* lp = Lb + (size_t)z * ((size_t)N_B * S_Q) + (size_t)n * S_Q + qA;
      lp[0]  = lsA[0];
      lp[16] = lsB[0];
    }
  } else {
    // single-pass finalize: O[q][v] = O^T[v][q] / l
    const float invA = 1.0f / lsA[0];
    const float invB = 1.0f / lsB[0];
    float* obA = Ob + ((size_t)n * S_Q + (size_t)qA) * DH + quad * 4;
    float* obB = obA + (size_t)16 * DH;
#pragma unroll
    for (int nt = 0; nt < 4; ++nt) {
      f32x4 oA, oB;
#pragma unroll
      for (int r = 0; r < 4; ++r) {
        oA[r] = accA[nt][r] * invA;
        oB[r] = accB[nt][r] * invB;
      }
      *(f32x4*)(obA + 16 * nt) = oA;
      *(f32x4*)(obB + 16 * nt) = oB;
    }
  }
}

// combine: O = (acc0 + acc1) / (l0 + l1); pure streaming, ~85 MB -> ~13 us
__global__ __launch_bounds__(256)
void sdpa_combine(const float* __restrict__ ws, float* __restrict__ Og) {
  constexpr size_t NSV = (size_t)N_B * S_Q * DH;
  constexpr size_t NS  = (size_t)N_B * S_Q;
  const size_t i = (size_t)blockIdx.x * 256 + threadIdx.x;  // f32x4 index
  const f32x4* A0 = (const f32x4*)ws;
  const f32x4* A1 = A0 + NSV / 4;
  const float* L0 = ws + 2 * NSV;
  const float* L1 = L0 + NS;
  const size_t qi = i >> 4;                                 // DH/4 = 16 per row
  const f32x4 a = A0[i], b = A1[i];
  const float inv = 1.0f / (L0[qi] + L1[qi]);
  f32x4 o;
#pragma unroll
  for (int r = 0; r < 4; ++r) o[r] = (a[r] + b[r]) * inv;
  ((f32x4*)Og)[i] = o;
}

extern "C" void kernel_launch(void* const* d_in, const int* in_sizes, int n_in,
                              void* d_out, int out_size, void* d_ws, size_t ws_size,
                              hipStream_t stream) {
  (void)in_sizes; (void)n_in; (void)out_size;
  const float* q = (const float*)d_in[0];
  const float* k = (const float*)d_in[1];
  const float* v = (const float*)d_in[2];
  const float* m = (const float*)d_in[3];
  float* o = (float*)d_out;

  constexpr size_t NSV = (size_t)N_B * S_Q * DH;
  constexpr size_t NS  = (size_t)N_B * S_Q;
  constexpr size_t WS_NEED = (2 * NSV + 2 * NS) * sizeof(float);  // ~34.1 MB

  if (d_ws != nullptr && ws_size >= WS_NEED) {
    float* ws = (float*)d_ws;
    dim3 grid(S_Q / BQ, N_B, 2);     // 1024 blocks -> 4 blocks/CU
    hipLaunchKernelGGL(sdpa_fwd, grid, dim3(256), 0, stream,
                       q, k, v, m, ws, ws + 2 * NSV, ITERS / 2);
    hipLaunchKernelGGL(sdpa_combine, dim3((unsigned)(NSV / 4 / 256)), dim3(256),
                       0, stream, (const float*)ws, o);
  } else {
    // fallback: single-pass, full KV per block
    dim3 grid(S_Q / BQ, N_B, 1);
    hipLaunchKernelGGL(sdpa_fwd, grid, dim3(256), 0, stream,
                       q, k, v, m, o, (float*)nullptr, ITERS);
  }
}

// Round 5
// 287.618 us; speedup vs baseline: 2.3454x; 2.3454x over previous
//
#include <hip/hip_runtime.h>
#include <cstdint>
#include <cstddef>

// ---------------------------------------------------------------------------
// NaiveSDPA: out[n,s,v] = softmax(Q·K^T / 8 + mask) · V ; f32 I/O, bf16 MFMA.
// v10r: identical resubmission of v10 (round-4 bench died in container
// acquisition, not in the kernel — no counters produced; OOB/divergence/
// resource audits all clean).
// v10: occupancy via structural register halving, not scheduling tricks.
// Evidence r0-r3: occupancy tiers are power-of-2 on COMBINED arch+acc VGPRs
// (2 waves/SIMD at <=256, 4 at <=128); the v6 dual-stream working set is
// ~156 regs and cannot be squeezed to 128 without ~1.1-1.5 GB of spills
// (r1, r3). So v10 changes the shape of the work per wave:
//   - 512-thread blocks: 8 waves x 16 q rows each (single stream), BQ=128.
//     acc 16+4, qf 8, pf 8 -> ~75 combined regs, fits the 128 tier loosely.
//   - role-split staging: waves 0-3 stage K, waves 4-7 stage V (wave-uniform
//     branch). Per-block staging work unchanged vs v6; per-thread halved;
//     staging regs 32 -> 16.
//   - per-q MFMA / exp / mask / staging costs identical to v6; only K/V LDS
//     re-reads double (~3 KB/blk-iter, negligible vs 128 B/cy/CU).
//   - 2 blocks/CU x 8 waves = 16 waves/CU = 50% occupancy (thread cap 2048
//     and reg tier agree); LDS 2x35KB <= 160KB. launch_bounds(512,4).
//   - KV-split + combine pass DELETED: grid (32,16)=512 blocks = exactly
//     2/CU in one pass; no workspace, no combine, no tail.
// Kept: ones-MFMA row-sum, setprio around MFMA clusters, double-buffered
// LDS with prefetch-between-phases, swizzled V^T, skewed K rows.
// Tripwire: WRITE_SIZE must stay ~16 MB (output only); ballooning = spills.
// ---------------------------------------------------------------------------

typedef __attribute__((ext_vector_type(8))) short short8;
typedef __attribute__((ext_vector_type(4))) short short4v;
typedef __attribute__((ext_vector_type(4))) float f32x4;
typedef __attribute__((ext_vector_type(4))) unsigned int uint4v;
typedef __attribute__((ext_vector_type(2))) unsigned int uint2v;

#define DEV __device__ __forceinline__

constexpr int N_B   = 16;
constexpr int S_Q   = 4096;
constexpr int S_KV  = 4096;
constexpr int DH    = 64;
constexpr int BQ    = 128;         // q rows per block (8 waves x 16)
constexpr int BK    = 64;
constexpr int ITERS = S_KV / BK;   // 64
constexpr int KSTR  = 72;          // shorts/row: 144B (skew 4 dwords)
constexpr int VSTR  = 68;          // shorts/row: 136B (16 slots + 4 pad)

#define LOG2E 1.44269504088896340736f

DEV unsigned short f2bf(float f) {           // RNE f32 -> bf16
  union { float f; unsigned int i; } x; x.f = f;
  unsigned int r = x.i + 0x7FFFu + ((x.i >> 16) & 1u);
  return (unsigned short)(r >> 16);
}

#if __has_builtin(__builtin_amdgcn_cvt_pk_bf16_f32)
typedef __attribute__((ext_vector_type(2))) __bf16 bf16x2v;
DEV unsigned int packrne(float a, float b) {   // bf16(a) lo | bf16(b) hi, RNE
  union { bf16x2v v; unsigned int u; } x;
  x.v = __builtin_amdgcn_cvt_pk_bf16_f32(a, b);
  return x.u;
}
#else
DEV unsigned int packrne(float a, float b) {
  union { float f; unsigned int u; } ua, ub; ua.f = a; ub.f = b;
  unsigned int ra = ua.u + 0x7FFFu + ((ua.u >> 16) & 1u);
  unsigned int rb = ub.u + 0x7FFFu + ((ub.u >> 16) & 1u);
  return __builtin_amdgcn_perm(rb, ra, 0x07060302u);
}
#endif

DEV f32x4 mfma16(short4v a, short4v b, f32x4 c) {
#if __has_builtin(__builtin_amdgcn_mfma_f32_16x16x16bf16_1k)
  return __builtin_amdgcn_mfma_f32_16x16x16bf16_1k(a, b, c, 0, 0, 0);
#elif __has_builtin(__builtin_amdgcn_mfma_f32_16x16x16_bf16)
  return __builtin_amdgcn_mfma_f32_16x16x16_bf16(a, b, c, 0, 0, 0);
#else
  asm volatile("v_mfma_f32_16x16x16_bf16 %0, %1, %2, %0\n\ts_nop 7\n\ts_nop 7"
               : "+v"(c) : "v"(a), "v"(b));
  return c;
#endif
}

// stage K tile (256 stager threads): thread tS owns 16B chunks
// (r=tS>>3, c=tS&7) and (r+32, c). L = {row r: lo,hi ; row r+32: lo,hi}.
DEV void stageK(unsigned short* buf, const f32x4* L, int tS) {
  const int r0 = tS >> 3, c = tS & 7;
  uint4v d0, d1;
  d0[0] = packrne(L[0][0], L[0][1]); d0[1] = packrne(L[0][2], L[0][3]);
  d0[2] = packrne(L[1][0], L[1][1]); d0[3] = packrne(L[1][2], L[1][3]);
  d1[0] = packrne(L[2][0], L[2][1]); d1[1] = packrne(L[2][2], L[2][3]);
  d1[2] = packrne(L[3][0], L[3][1]); d1[3] = packrne(L[3][2], L[3][3]);
  *(uint4v*)&buf[r0 * KSTR + c * 8]        = d0;
  *(uint4v*)&buf[(r0 + 32) * KSTR + c * 8] = d1;
}

// stage V^T (256 stager threads): thread tS loaded L[i] =
// V[kv=4*(tS>>4)+i][4*(tS&15)..+3] (coalesced per 16-lane phase). Writes
// chunk a=tS>>4 of vcol=4x+j (x=tS&15) at slot (a+x)&15: conflict-free.
DEV void stageV(unsigned short* buf, const f32x4* L, int tS) {
  const int a = tS >> 4;          // kv-chunk
  const int x = tS & 15;          // vcol>>2
  const int slot = (a + x) & 15;
#pragma unroll
  for (int j = 0; j < 4; ++j) {
    uint2v d;
    d[0] = packrne(L[0][j], L[1][j]);
    d[1] = packrne(L[2][j], L[3][j]);
    *(uint2v*)&buf[(x * 4 + j) * VSTR + slot * 4] = d;
  }
}

__global__ __launch_bounds__(512, 4)
void sdpa_fwd(const float* __restrict__ Qg,
              const float* __restrict__ Kg,
              const float* __restrict__ Vg,
              const float* __restrict__ Mg,
              float* __restrict__ Og)
{
  __shared__ __align__(16) unsigned short ldsK[2][BK * KSTR];  // 2 x 9216 B
  __shared__ __align__(16) unsigned short ldsV[2][DH * VSTR];  // 2 x 8704 B

  const int n    = blockIdx.y;
  const int q0   = blockIdx.x * BQ;
  const int t    = threadIdx.x;
  const int w    = t >> 6;          // wave 0..7: owns q rows q0+16w..+15
  const int lane = t & 63;
  const int l15  = lane & 15;
  const int quad = lane >> 4;
  const int qrow = q0 + w * 16 + l15;

  // ---- Q B-frags (single 16-q stream per wave)
  short8 qf0, qf1;
  {
    const float* qp = Qg + ((size_t)n * S_Q + (size_t)qrow) * DH + quad * 8;
#pragma unroll
    for (int j = 0; j < 8; ++j) {
      qf0[j] = (short)f2bf(qp[j]);
      qf1[j] = (short)f2bf(qp[32 + j]);
    }
  }

  // ---- staging role: waves 0-3 stage K, waves 4-7 stage V (wave-uniform)
  const bool isK = (w < 4);
  const int  tS  = t & 255;
  const float* sgp =
      isK ? Kg + ((size_t)n * S_KV + (size_t)(tS >> 3)) * DH + (tS & 7) * 8
          : Vg + ((size_t)n * S_KV + (size_t)(tS >> 4) * 4) * DH + (tS & 15) * 4;

  const float* mrow = Mg + (size_t)qrow * S_KV + quad * 4;

  // ---- O^T accumulators (C-layout: row v=16nt+quad*4+r, col q=l15)
  f32x4 acc[4];
#pragma unroll
  for (int nt = 0; nt < 4; ++nt)
#pragma unroll
    for (int r = 0; r < 4; ++r) acc[nt][r] = 0.0f;

  // ---- l accumulator via ones-MFMA (all rows equal; read [0] at the end)
  f32x4 ls = {0.f, 0.f, 0.f, 0.f};
  const short4v onesf = {(short)0x3F80, (short)0x3F80,
                         (short)0x3F80, (short)0x3F80};  // bf16 1.0

  // ---- prologue: load + stage tile 0 (role-split)
  {
    f32x4 L[4];
    if (isK) {
      L[0] = *(const f32x4*)(sgp);
      L[1] = *(const f32x4*)(sgp + 4);
      L[2] = *(const f32x4*)(sgp + 32 * DH);
      L[3] = *(const f32x4*)(sgp + 32 * DH + 4);
      stageK(&ldsK[0][0], L, tS);
    } else {
#pragma unroll
      for (int i = 0; i < 4; ++i) L[i] = *(const f32x4*)(sgp + i * DH);
      stageV(&ldsV[0][0], L, tS);
    }
  }
  __syncthreads();

  for (int it = 0; it < ITERS; ++it) {
    const int p   = it & 1;
    const int kv0 = it * BK;
    const bool more = (it + 1 < ITERS);

    // ---- phase 1: per-h { kf read, mask load, QK MFMA, exp, pack }
    short4v pf[4];
#pragma unroll
    for (int h = 0; h < 4; ++h) {
      const short8 kf0 =
          *(const short8*)&ldsK[p][(l15 + 16 * h) * KSTR + quad * 8];
      const short8 kf1 =
          *(const short8*)&ldsK[p][(l15 + 16 * h) * KSTR + (quad + 4) * 8];
      const f32x4 mk = *(const f32x4*)(mrow + kv0 + 16 * h);
      f32x4 c = {0.f, 0.f, 0.f, 0.f};
      __builtin_amdgcn_s_setprio(1);
      c = __builtin_amdgcn_mfma_f32_16x16x32_bf16(kf0, qf0, c, 0, 0, 0);
      c = __builtin_amdgcn_mfma_f32_16x16x32_bf16(kf1, qf1, c, 0, 0, 0);
      __builtin_amdgcn_s_setprio(0);
      float e[4];
#pragma unroll
      for (int r = 0; r < 4; ++r)
        e[r] = __builtin_amdgcn_exp2f(fmaf(c[r], 0.125f, mk[r]) * LOG2E);
      union { uint2v u; short4v s; } ue;
      ue.u[0] = packrne(e[0], e[1]);
      ue.u[1] = packrne(e[2], e[3]);
      pf[h] = ue.s;
    }

    // ---- issue next-tile global loads (covered by ls+PV MFMAs below)
    f32x4 L[4];
    if (more) {
      const float* np = sgp + (size_t)(kv0 + BK) * DH;
      if (isK) {
        L[0] = *(const f32x4*)(np);
        L[1] = *(const f32x4*)(np + 4);
        L[2] = *(const f32x4*)(np + 32 * DH);
        L[3] = *(const f32x4*)(np + 32 * DH + 4);
      } else {
#pragma unroll
        for (int i = 0; i < 4; ++i) L[i] = *(const f32x4*)(np + i * DH);
      }
    }

    __builtin_amdgcn_s_setprio(1);
    // row sums on the matrix pipe
#pragma unroll
    for (int h = 0; h < 4; ++h) ls = mfma16(onesf, pf[h], ls);

    // PV: O^T += V^T·P^T
    // vf = V^T[vcol=l15+16nt][kv chunk c=4h+quad] at slot (c + vcol/4)&15
#pragma unroll
    for (int nt = 0; nt < 4; ++nt) {
      const int vcol = l15 + 16 * nt;
      const int xr   = (l15 >> 2) + 4 * nt;
#pragma unroll
      for (int h = 0; h < 4; ++h) {
        const int slot = ((4 * h + quad) + xr) & 15;
        short4v vf = *(const short4v*)&ldsV[p][vcol * VSTR + slot * 4];
        acc[nt] = mfma16(vf, pf[h], acc[nt]);
      }
    }
    __builtin_amdgcn_s_setprio(0);

    // ---- write-late: pack + ds_write the prefetched tile (role-split)
    if (more) {
      if (isK) stageK(&ldsK[p ^ 1][0], L, tS);
      else     stageV(&ldsV[p ^ 1][0], L, tS);
    }
    __syncthreads();
  }

  // ---- epilogue: O[q][v] = O^T[v][q] / l ; coalesced f32x4 stores
  const float inv = 1.0f / ls[0];
  float* ob = Og + ((size_t)n * S_Q + (size_t)qrow) * DH + quad * 4;
#pragma unroll
  for (int nt = 0; nt < 4; ++nt) {
    f32x4 o;
#pragma unroll
    for (int r = 0; r < 4; ++r) o[r] = acc[nt][r] * inv;
    *(f32x4*)(ob + 16 * nt) = o;
  }
}

extern "C" void kernel_launch(void* const* d_in, const int* in_sizes, int n_in,
                              void* d_out, int out_size, void* d_ws, size_t ws_size,
                              hipStream_t stream) {
  (void)in_sizes; (void)n_in; (void)d_ws; (void)ws_size; (void)out_size;
  const float* q = (const float*)d_in[0];
  const float* k = (const float*)d_in[1];
  const float* v = (const float*)d_in[2];
  const float* m = (const float*)d_in[3];
  float* o = (float*)d_out;

  dim3 grid(S_Q / BQ, N_B);   // (32, 16) = 512 blocks of 512 thr = 2 blocks/CU
  dim3 block(512);
  hipLaunchKernelGGL(sdpa_fwd, grid, block, 0, stream, q, k, v, m, o);
}